// Round 4
// baseline (215.229 us; speedup 1.0000x reference)
//
#include <hip/hip_runtime.h>

// LocalitySelfAttention: B=2, N=4096, DIM=512, H=8, d=64 (INNER=512)
// bf16 MFMA (16x16x32), fp32 accumulate. Head (b,h) = contiguous (4096x64)
// tile at offset (b*8+h)<<18 of the (8192x512) activation matrices.

typedef __bf16 bf16;
typedef __bf16 bf16x8 __attribute__((ext_vector_type(8)));
typedef __bf16 bf16x4 __attribute__((ext_vector_type(4)));
typedef float  f32x4  __attribute__((ext_vector_type(4)));

#define MFMA_BF16(a, b, c) __builtin_amdgcn_mfma_f32_16x16x32_bf16((a), (b), (c), 0, 0, 0)

__device__ __forceinline__ void gld_lds16(void* lds, const void* g) {
  __builtin_amdgcn_global_load_lds(
      (const __attribute__((address_space(1))) void*)g,
      (__attribute__((address_space(3))) void*)lds, 16, 0, 0);
}

// ---------------- converters ----------------

__global__ void cast4_kernel(const float* __restrict__ in, bf16* __restrict__ out, int n4) {
  int i = blockIdx.x * 256 + threadIdx.x;
  if (i >= n4) return;
  float4 v = ((const float4*)in)[i];
  bf16x4 o;
  o[0] = (bf16)v.x; o[1] = (bf16)v.y; o[2] = (bf16)v.z; o[3] = (bf16)v.w;
  *(bf16x4*)(out + 4 * i) = o;
}

// out (C x 512) = in (512 x C)^T, f32 -> bf16, LDS-tiled
__global__ void wtrans_kernel(const float* __restrict__ in, bf16* __restrict__ out, int C) {
  __shared__ float tile[64 * 65];
  const int t = threadIdx.x;
  const int c0 = blockIdx.x * 64, r0 = blockIdx.y * 64;
#pragma unroll
  for (int p = 0; p < 16; p++) {
    int idx = p * 256 + t, r = idx >> 6, c = idx & 63;
    tile[r * 65 + c] = in[(r0 + r) * C + c0 + c];
  }
  __syncthreads();
#pragma unroll
  for (int p = 0; p < 16; p++) {
    int idx = p * 256 + t, c = idx >> 6, r = idx & 63;
    out[(size_t)(c0 + c) * 512 + r0 + r] = (bf16)tile[r * 65 + c];
  }
}

// per-head (4096x64) -> (64x4096), LDS-tiled. grid (64 n-tiles, 16 heads)
__global__ void vtrans_kernel(const bf16* __restrict__ V, bf16* __restrict__ Vt) {
  __shared__ bf16 tile[64 * 65];
  const int t = threadIdx.x;
  const size_t base = (size_t)blockIdx.y << 18;
  const int n0 = blockIdx.x * 64;
#pragma unroll
  for (int p = 0; p < 16; p++) {
    int idx = p * 256 + t, r = idx >> 6, c = idx & 63;
    tile[r * 65 + c] = V[base + (size_t)(n0 + r) * 64 + c];
  }
  __syncthreads();
#pragma unroll
  for (int p = 0; p < 16; p++) {
    int idx = p * 256 + t, d = idx >> 6, n = idx & 63;
    Vt[base + (size_t)d * 4096 + n0 + n] = tile[n * 65 + d];
  }
}

// ---------------- GEMM: C(M x *) = A(Mx512) * Bt(*x512)^T ----------------

template<int EPI, int WNT>
__global__ __launch_bounds__(256) void gemm_bt(
    const bf16* __restrict__ A, const bf16* __restrict__ Bt,
    bf16* __restrict__ oQ, bf16* __restrict__ oK, bf16* __restrict__ oV,
    float* __restrict__ oC, const float* __restrict__ bias,
    const float* __restrict__ temp)
{
  __shared__ bf16 As[128 * 32];
  __shared__ bf16 Bs[WNT * 32 * 32];

  const int t    = threadIdx.x;
  const int lane = t & 63;
  const int w    = t >> 6;
  const int mm   = lane & 15;
  const int q    = lane >> 4;
  const int wm   = w >> 1, wn = w & 1;
  const int m0   = blockIdx.y * 128;
  const int n0   = blockIdx.x * (WNT * 32);

  const int srow = t >> 2, sch = t & 3;
  const int gch  = sch ^ ((srow >> 1) & 3);
  const bf16* Ab = A  + (m0 + srow) * 512 + gch * 8;
  const bf16* Bb = Bt + (n0 + srow) * 512 + gch * 8;
  bf16* Asl = As + t * 8;
  bf16* Bsl = Bs + t * 8;

  const int fslot = (q ^ ((mm >> 1) & 3)) * 8;

  const f32x4 zero4 = {0.f, 0.f, 0.f, 0.f};
  f32x4 acc[4][WNT];
#pragma unroll
  for (int i = 0; i < 4; i++)
#pragma unroll
    for (int j = 0; j < WNT; j++) acc[i][j] = zero4;

  for (int k0 = 0; k0 < 512; k0 += 32) {
    __syncthreads();
    gld_lds16(Asl,        Ab + k0);
    gld_lds16(Asl + 2048, Ab + 64 * 512 + k0);
    gld_lds16(Bsl,        Bb + k0);
    if (WNT == 4) gld_lds16(Bsl + 2048, Bb + 64 * 512 + k0);
    __syncthreads();

    bf16x8 af[4], bfv[WNT];
#pragma unroll
    for (int i = 0; i < 4; i++)
      af[i] = *(const bf16x8*)(As + (wm * 64 + i * 16 + mm) * 32 + fslot);
#pragma unroll
    for (int j = 0; j < WNT; j++)
      bfv[j] = *(const bf16x8*)(Bs + (wn * (WNT * 16) + j * 16 + mm) * 32 + fslot);

#pragma unroll
    for (int i = 0; i < 4; i++)
#pragma unroll
      for (int j = 0; j < WNT; j++)
        acc[i][j] = MFMA_BF16(af[i], bfv[j], acc[i][j]);
  }

  if (EPI == 0) {
    // fold exp(temperature) AND log2(e) into Q so attention uses raw exp2
    const float scale = __expf(temp[0]) * 1.44269504088896f;
#pragma unroll
    for (int i = 0; i < 4; i++) {
      const int row = m0 + wm * 64 + i * 16 + q * 4;
#pragma unroll
      for (int j = 0; j < WNT; j++) {
        const int col = n0 + wn * (WNT * 16) + j * 16 + mm;
        bf16* dst; int c2; float s;
        if (col < 512)       { dst = oQ; c2 = col;        s = scale; }
        else if (col < 1024) { dst = oK; c2 = col - 512;  s = 1.0f;  }
        else                 { dst = oV; c2 = col - 1024; s = 1.0f;  }
#pragma unroll
        for (int r = 0; r < 4; r++)
          dst[(size_t)(row + r) * 512 + c2] = (bf16)(acc[i][j][r] * s);
      }
    }
  } else {
#pragma unroll
    for (int i = 0; i < 4; i++) {
      const int row = m0 + wm * 64 + i * 16 + q * 4;
#pragma unroll
      for (int j = 0; j < WNT; j++) {
        const int col = n0 + wn * (WNT * 16) + j * 16 + mm;
        const float b = bias[col];
#pragma unroll
        for (int r = 0; r < 4; r++)
          oC[(size_t)(row + r) * 512 + col] = acc[i][j][r] + b;
      }
    }
  }
}

// ---------------- flash attention v4: double-buffered KV staging ----------
// 4 waves x 64 Q-rows = 256-row tile; KV tile 32, Ks/Vs double-buffered.
// Stage(next) is issued AFTER the barrier so the barrier's vmcnt(0) drain
// only waits on the stage issued one full compute-phase earlier (latency
// hidden). S^T = K*Q^T; p = exp2(s) (log2e*exp(temp) folded into Q, no max
// needed); P goes through swizzled LDS (16B-chunk XOR key=row&3, stride 32:
// b64 writes + b128 reads both conflict-free-minimal); row sums via
// ones-MFMA. Regs cap occupancy at 3 waves/SIMD -> grid 768 = 3 blocks/CU.

template<int SPLIT>
__global__ __launch_bounds__(256, 3) void attn_kernel(
    const bf16* __restrict__ Q, const bf16* __restrict__ Kb,
    const bf16* __restrict__ Vt, bf16* __restrict__ O,
    float* __restrict__ Opart, float* __restrict__ Lpart)
{
  __shared__ bf16 Ks[2][32 * 64];   // [kv][d], 16B-chunk swizzle key = kv&7
  __shared__ bf16 Vs[2][64 * 32];   // [d][kv], 16B-chunk swizzle key = (d>>2)&3
  __shared__ bf16 Ps[4][64 * 32];   // per-wave P, 16B-chunk swizzle key = row&3

  const int t    = threadIdx.x;
  const int lane = t & 63;
  const int w    = t >> 6;
  const int mm   = lane & 15;
  const int q    = lane >> 4;
  const int bh   = blockIdx.y;
  const int q0   = blockIdx.x * 256;
  const int z    = blockIdx.z;
  const size_t hb = (size_t)bh << 18;
  const bf16* Qh = Q  + hb;
  const bf16* Kh = Kb + hb;
  const bf16* Vh = Vt + hb;
  const int q0w  = q0 + w * 64;     // this wave's first Q row (64-aligned)

  // kv tile range (tiles of 32; 128 total)
  int tlo, tn;
  if (SPLIT == 1)      { tlo = 0;                              tn = 128; }
  else                 { tlo = (z == 0) ? 0 : (z == 1 ? 43 : 86); tn = (z == 2) ? 42 : 43; }

  // Q B-frags, register-resident: Q[q0w+i*16+mm][ks*32+q*8+j]
  bf16x8 qf[4][2];
#pragma unroll
  for (int i = 0; i < 4; i++)
#pragma unroll
    for (int ks = 0; ks < 2; ks++)
      qf[i][ks] = *(const bf16x8*)(Qh + (size_t)(q0w + i * 16 + mm) * 64 + ks * 32 + q * 8);

  const f32x4 zero4 = {0.f, 0.f, 0.f, 0.f};
  f32x4 o[4][4];
  f32x4 lacc[4];
#pragma unroll
  for (int i = 0; i < 4; i++) {
    lacc[i] = zero4;
#pragma unroll
    for (int dj = 0; dj < 4; dj++) o[i][dj] = zero4;
  }

  bf16x8 onesf;
#pragma unroll
  for (int e = 0; e < 8; e++) onesf[e] = (bf16)1.0f;

  // staging maps (256 threads x 16B = one 32x64 tile per matrix)
  const int skv = t >> 3, sc8 = t & 7;
  const int gK  = sc8 ^ (skv & 7);            // K global chunk for lds slot
  const int sd  = t >> 2, sc4 = t & 3;
  const int gV  = sc4 ^ ((sd >> 2) & 3);      // V global chunk for lds slot
  const bf16* KgB = Kh + (size_t)skv * 64 + gK * 8;   // + kv0*64
  const bf16* VgB = Vh + (size_t)sd * 4096 + gV * 8;  // + kv0
  bf16* pw = &Ps[w][0];

  // prologue stage of tile 0 into buf 0
  {
    const int kv0 = tlo * 32;
    gld_lds16(&Ks[0][t * 8], KgB + (size_t)kv0 * 64);
    gld_lds16(&Vs[0][t * 8], VgB + kv0);
  }

  for (int it = 0; it < tn; it++) {
    const int buf = it & 1;
    __syncthreads();   // drains stage(it) — issued one compute-phase ago
    if (it + 1 < tn) {
      const int kvn = (tlo + it + 1) * 32;
      gld_lds16(&Ks[buf ^ 1][t * 8], KgB + (size_t)kvn * 64);
      gld_lds16(&Vs[buf ^ 1][t * 8], VgB + kvn);
    }

    const int kv0 = (tlo + it) * 32;
    const bf16* ks = &Ks[buf][0];
    const bf16* vs = &Vs[buf][0];

    // S^T = K * Q^T  (A = K rows = kv, B = Q), then p = exp2(s) -> Ps
#pragma unroll
    for (int jm = 0; jm < 2; jm++) {
      const int krow = jm * 16 + mm;
      const int sw = krow & 7;
      bf16x8 kf0 = *(const bf16x8*)(ks + krow * 64 + ((q)     ^ sw) * 8);
      bf16x8 kf1 = *(const bf16x8*)(ks + krow * 64 + ((4 + q) ^ sw) * 8);
#pragma unroll
      for (int i = 0; i < 4; i++) {
        f32x4 zacc = MFMA_BF16(kf0, qf[i][0], zero4);
        f32x4 sv   = MFMA_BF16(kf1, qf[i][1], zacc);
        // diagonal self-mask: block-diag when row-block == col-block
        if ((q0w + i * 16) == (kv0 + jm * 16) && (mm >> 2) == q)
          sv[mm & 3] = -1e30f;
        bf16x4 pk;
#pragma unroll
        for (int r = 0; r < 4; r++)
          pk[r] = (bf16)__builtin_amdgcn_exp2f(sv[r]);
        // write 8B at row i*16+mm, kv-chunk (jm*2 + (q>>1)) ^ (mm&3), half q&1
        *(bf16x4*)(pw + (i * 16 + mm) * 32 +
                   (((jm * 2 + (q >> 1)) ^ (mm & 3)) * 8) + (q & 1) * 4) = pk;
      }
    }
    __asm__ volatile("s_waitcnt lgkmcnt(0)" ::: "memory");

    // O += P V ; row sums via ones-MFMA
    bf16x8 vf[4];
#pragma unroll
    for (int dj = 0; dj < 4; dj++) {
      const int d = dj * 16 + mm;
      vf[dj] = *(const bf16x8*)(vs + d * 32 + ((q ^ ((d >> 2) & 3)) * 8));
    }
#pragma unroll
    for (int i = 0; i < 4; i++) {
      bf16x8 pf = *(const bf16x8*)(pw + (i * 16 + mm) * 32 + ((q ^ (mm & 3)) * 8));
#pragma unroll
      for (int dj = 0; dj < 4; dj++)
        o[i][dj] = MFMA_BF16(pf, vf[dj], o[i][dj]);
      lacc[i] = MFMA_BF16(pf, onesf, lacc[i]);
    }
  }

  if (SPLIT == 1) {
    bf16* Oh = O + hb;
#pragma unroll
    for (int i = 0; i < 4; i++) {
      const int rowb = q0w + i * 16 + q * 4;
#pragma unroll
      for (int r = 0; r < 4; r++) {
        const float rinv = 1.0f / lacc[i][r];
#pragma unroll
        for (int dj = 0; dj < 4; dj++)
          Oh[(size_t)(rowb + r) * 64 + dj * 16 + mm] = (bf16)(o[i][dj][r] * rinv);
      }
    }
  } else {
    float* Op = Opart + ((size_t)z << 22) + hb;
    float* Lp = Lpart + (z << 16) + (bh << 12);
#pragma unroll
    for (int i = 0; i < 4; i++) {
      const int rowb = q0w + i * 16 + q * 4;
      if (mm == 0) {
#pragma unroll
        for (int r = 0; r < 4; r++) Lp[rowb + r] = lacc[i][r];
      }
#pragma unroll
      for (int dj = 0; dj < 4; dj++)
#pragma unroll
        for (int r = 0; r < 4; r++)
          Op[(size_t)(rowb + r) * 64 + dj * 16 + mm] = o[i][dj][r];
    }
  }
}

// merge kv-split partials: Ob = (sum_z Oz) / (sum_z lz)
template<int SPLIT>
__global__ void merge_kernel(const float* __restrict__ Op, const float* __restrict__ Lp,
                             bf16* __restrict__ Ob) {
  const int g = blockIdx.x * 256 + threadIdx.x;
  const int f = g * 4;
  const int row = f >> 6;
  float l = 0.f;
  float4 a = {0.f, 0.f, 0.f, 0.f};
#pragma unroll
  for (int zz = 0; zz < SPLIT; zz++) {
    l += Lp[(zz << 16) + row];
    const float4 b = *(const float4*)(Op + ((size_t)zz << 22) + f);
    a.x += b.x; a.y += b.y; a.z += b.z; a.w += b.w;
  }
  const float rinv = 1.0f / l;
  bf16x4 o;
  o[0] = (bf16)(a.x * rinv);
  o[1] = (bf16)(a.y * rinv);
  o[2] = (bf16)(a.z * rinv);
  o[3] = (bf16)(a.w * rinv);
  *(bf16x4*)(Ob + f) = o;
}

// ---------------- launch ----------------

extern "C" void kernel_launch(void* const* d_in, const int* in_sizes, int n_in,
                              void* d_out, int out_size, void* d_ws, size_t ws_size,
                              hipStream_t stream) {
  const float* x      = (const float*)d_in[0];
  const float* w_qkv  = (const float*)d_in[1];
  const float* temp   = (const float*)d_in[2];
  const float* w_out  = (const float*)d_in[3];
  const float* b_out  = (const float*)d_in[4];
  float* out          = (float*)d_out;

  char* ws = (char*)d_ws;
  bf16*  Xb    = (bf16*)(ws);                         // 8 MB
  bf16*  Wt    = (bf16*)(ws + (size_t)(8u  << 20));   // 1.5 MB
  bf16*  Qb    = (bf16*)(ws + (size_t)(10u << 20));   // 8 MB
  bf16*  Kb    = (bf16*)(ws + (size_t)(18u << 20));   // 8 MB
  bf16*  Vb    = (bf16*)(ws + (size_t)(26u << 20));   // 8 MB
  bf16*  Vtb   = (bf16*)(ws + (size_t)(34u << 20));   // 8 MB
  bf16*  Ob    = (bf16*)(ws + (size_t)(42u << 20));   // 8 MB
  bf16*  Wot   = (bf16*)(ws + (size_t)(50u << 20));   // 0.5 MB
  float* Lpart = (float*)(ws + (size_t)(51u << 20));  // 3 x 256 KB
  float* Opart = (float*)(ws + (size_t)(52u << 20));  // 3 x 16.78 MB

  const int split = (ws_size >= ((size_t)103u << 20)) ? 3 : 1;

  cast4_kernel<<<4096, 256, 0, stream>>>(x, Xb, (8192 * 512) / 4);
  wtrans_kernel<<<dim3(24, 8), 256, 0, stream>>>(w_qkv, Wt, 1536);
  wtrans_kernel<<<dim3(8, 8), 256, 0, stream>>>(w_out, Wot, 512);

  gemm_bt<0, 4><<<dim3(12, 64), 256, 0, stream>>>(Xb, Wt, Qb, Kb, Vb, nullptr, nullptr, temp);

  vtrans_kernel<<<dim3(64, 16), 256, 0, stream>>>(Vb, Vtb);

  if (split == 3) {
    attn_kernel<3><<<dim3(16, 16, 3), 256, 0, stream>>>(Qb, Kb, Vtb, nullptr, Opart, Lpart);
    merge_kernel<3><<<4096, 256, 0, stream>>>(Opart, Lpart, Ob);
  } else {
    attn_kernel<1><<<dim3(16, 16, 1), 256, 0, stream>>>(Qb, Kb, Vtb, Ob, nullptr, nullptr);
  }

  gemm_bt<1, 2><<<dim3(8, 64), 256, 0, stream>>>(Ob, Wot, nullptr, nullptr, nullptr, out, b_out, nullptr);
}